// Round 12
// baseline (203.823 us; speedup 1.0000x reference)
//
#include <hip/hip_runtime.h>
#include <stdint.h>

#define N_ROWS 4096
#define N_DIM  2048
#define MARGIN 0.3f
#define NITER  (N_DIM / 64)  // BK=64 -> 32 K-iterations
#define FLTMAX 3.402823466e+38f

// Tiling: 64 (A-rows) x 128 (B-cols) tiles. bi in [0,64), bj in [0,32),
// tiles with bi <= 2*bj+1 (covers all upper-triangle cells) -> 1056 blocks.
// XCD-paired decode (R9, measured: FETCH -18%): XCD x owns bj in
// {2x, 31-2x, 2x+1, 30-2x}.
#define NBI 64
#define NBJ 32
#define NBLOCKS 1056         // 132 x 8

typedef __attribute__((ext_vector_type(8))) short short8;
typedef __attribute__((ext_vector_type(4))) float floatx4;

// Packed layout ("fragment order"): for 16-row group g (256 total) and k-chunk
// c (32 k each, 64 total), a 1 KB block at shorts-offset (g*64+c)*512. Lane l's
// 16 B fragment at l*8 shorts = row g*16+(l&15), k c*32+(l>>4)*8..

__device__ inline unsigned short f2bf_rne(float f) {
  unsigned u = __float_as_uint(f);
  unsigned r = 0x7fffu + ((u >> 16) & 1u);
  return (unsigned short)((u + r) >> 16);
}
__device__ inline float bf2f(unsigned short h) {
  return __uint_as_float(((unsigned)h) << 16);
}

// Async global->LDS DMA, 16 B per lane. LDS dest = firstlane base + lane*16.
__device__ inline void gld_lds16(const void* g, void* l) {
  __builtin_amdgcn_global_load_lds(
      (const __attribute__((address_space(1))) void*)g,
      (__attribute__((address_space(3))) void*)l, 16, 0, 0);
}

// ---------------------------------------------------------------------------
// Kernel 1, R12 (= R11 prep + absorbed init): TLP prep, 1024 blocks (4/CU),
// block (g = b>>2, cq = b&3) stages 32 KB fp32 via gld_lds, one barrier,
// convert+repack+store. sq partials now go NON-atomically to sq4[cq][row]
// (dist sums the 4 quarters) -> no pre-zero needed. cq==0 blocks init
// ap/an; block 0 zeroes the dist completion counter. Same-stream ordering
// (prep fully precedes dist) makes all init race-free. init_kernel deleted.
// ---------------------------------------------------------------------------
__global__ __launch_bounds__(256) void prep_kernel(
    const float* __restrict__ X, unsigned short* __restrict__ Xp,
    float* __restrict__ sq4, unsigned* __restrict__ ap,
    unsigned* __restrict__ an, unsigned* __restrict__ counter)
{
  __shared__ __align__(16) float chunkf[8192];   // 32 KB: [row r][128 units]
  __shared__ float part[4][16];
  const int b = blockIdx.x;
  const int g = b >> 2, cq = b & 3;
  const int t = threadIdx.x;
  const int r = t & 15, j = (t >> 4) & 3, w = t >> 6;

  // Stage: rows [g*16,g*16+16) x bytes [cq*2048, cq*2048+2048) of each row.
  // LDS slot v (row rr=v>>7, unit m=v&127) holds global unit m^(rr&7) of the
  // row-quarter (source-side swizzle) -> b128 reads spread 8-way max.
  const char* Xb = (const char*)X + (size_t)g * 16 * 8192 + (size_t)cq * 2048;
#pragma unroll
  for (int q = 0; q < 8; ++q) {
    const unsigned v = q * 256 + t;
    const unsigned rr = v >> 7, m = v & 127;
    gld_lds16(Xb + (size_t)rr * 8192 + (size_t)(m ^ (rr & 7)) * 16,
              (char*)chunkf + (size_t)v * 16);
  }
  __syncthreads();   // full drain: all 16 rows staged; cross-wave reads safe

  unsigned short* Op = Xp + (size_t)g * 64 * 512 + (size_t)(j * 16 + r) * 8;
  float acc = 0.f;
#pragma unroll
  for (int sp = 0; sp < 4; ++sp) {
    const int cl = w + sp * 4;                   // local chunk in [0,16)
    const int c = cq * 16 + cl;                  // global chunk in [0,64)
    const unsigned m0 = (unsigned)cl * 8 + j * 2;  // 16B-unit within quarter-row
    const float4 v0 = *(const float4*)&chunkf[(r * 128 + (m0 ^ (r & 7))) * 4];
    const float4 v1 = *(const float4*)&chunkf[(r * 128 + ((m0 + 1) ^ (r & 7))) * 4];
    short8 o;
    o[0] = (short)f2bf_rne(v0.x); o[1] = (short)f2bf_rne(v0.y);
    o[2] = (short)f2bf_rne(v0.z); o[3] = (short)f2bf_rne(v0.w);
    o[4] = (short)f2bf_rne(v1.x); o[5] = (short)f2bf_rne(v1.y);
    o[6] = (short)f2bf_rne(v1.z); o[7] = (short)f2bf_rne(v1.w);
#pragma unroll
    for (int e = 0; e < 8; ++e) {
      float f = bf2f((unsigned short)o[e]);
      acc = fmaf(f, f, acc);
    }
    *(short8*)(Op + (size_t)c * 512) = o;
  }
  acc += __shfl_xor(acc, 16, 64);
  acc += __shfl_xor(acc, 32, 64);
  if ((t & 63) < 16) part[w][r] = acc;
  __syncthreads();
  if (t < 16) {
    float s4 = part[0][t] + part[1][t] + part[2][t] + part[3][t];
    sq4[cq * N_ROWS + g * 16 + t] = s4;          // non-atomic quarter partial
    if (cq == 0) {
      ap[g * 16 + t] = 0u;                       // max identity (dist >= 0)
      an[g * 16 + t] = 0x7f7fffffu;              // FLT_MAX bits
    }
  }
  if (b == 0 && t == 0) *counter = 0u;           // dist completion counter
}

// ---------------------------------------------------------------------------
// Kernel 2, R12 (= R9/R11 dist + absorbed finalize): 64x128 tile, 1x4 wave
// grid, acc[4][2], A in LDS dbuf via gld_lds (one __syncthreads/iter), B
// direct global->register prefetch, XCD-paired decode. sqi/sqj now sum the
// 4 sq4 quarters at load time. After the atomic epilogue, the LAST block
// (device-scope counter, threadfence release/acquire) performs the loss
// reduction; it reads ap/an via no-op atomic RMWs (device-coherent across
// XCD L2s — plain loads could see stale lines, G16). finalize_kernel deleted.
// ---------------------------------------------------------------------------
__global__ __launch_bounds__(256, 4) void dist_kernel(
    const unsigned short* __restrict__ Xp, const float* __restrict__ sq4,
    const int* __restrict__ lab, unsigned* __restrict__ ap,
    unsigned* __restrict__ an, unsigned* __restrict__ counter,
    float* __restrict__ out)
{
  __shared__ __align__(16) unsigned short As[2][4096];   // 2 x 8 KB (64 rows x 64 k)
  __shared__ float sqi[64], sqj[128];
  __shared__ int labi[64], labj[128];

  // R9 decode: x = target XCD (round-robin assumption), r = slot in [0,132).
  int bi, bj;
  {
    const int x = (int)(blockIdx.x & 7);
    int r = (int)(blockIdx.x >> 3);
    const int c0 = 4 * x + 2;            // bj = 2x      (bi <= 4x+1)
    const int c1 = 64 - 4 * x;           // bj = 31-2x   (bi <= 63-4x)
    const int c2 = 4 * x + 4;            // bj = 2x+1    (bi <= 4x+3)
    if (r < c0)                { bj = 2 * x;      bi = r; }
    else if (r < c0 + c1)      { bj = 31 - 2 * x; bi = r - c0; }
    else if (r < c0 + c1 + c2) { bj = 2 * x + 1;  bi = r - c0 - c1; }
    else                       { bj = 30 - 2 * x; bi = r - c0 - c1 - c2; }
  }

  const int t = threadIdx.x;
  const int lane = t & 63, w = t >> 6;     // 4 waves, 1x4 grid: wave w owns
                                           // cols [w*32, w*32+32), all 64 rows

  if (t < 64) {
    int rr = bi * 64 + t;
    sqi[t] = sq4[rr] + sq4[N_ROWS + rr] + sq4[2 * N_ROWS + rr] + sq4[3 * N_ROWS + rr];
    labi[t] = lab[rr];
  } else if (t < 192) {
    int cc = bj * 128 + (t - 64);
    sqj[t - 64] = sq4[cc] + sq4[N_ROWS + cc] + sq4[2 * N_ROWS + cc] + sq4[3 * N_ROWS + cc];
    labj[t - 64] = lab[cc];
  }

  // A staging: identity chunk map, 512 x 16B units (2/thread). unit u: group
  // gg = u>>7 (wave-uniform), off = u&127 (lane-contiguous) -> legal gld_lds.
  unsigned gA[2], loA[2];
#pragma unroll
  for (int q = 0; q < 2; ++q) {
    const unsigned u = q * 256 + t;
    gA[q] = ((unsigned)(bi * 4 + (u >> 7)) * 64) * 512 + (u & 127) * 8;
    loA[q] = u * 8;
  }
  // B direct: wave w's col 16-groups are (w*2) and (w*2+1). Fragment for
  // (ni, it, kh) at Bb[ni] + it*1024 + kh*512 (shorts), per-lane 16 B.
  const unsigned short* Bb[2];
#pragma unroll
  for (int ni = 0; ni < 2; ++ni)
    Bb[ni] = Xp + ((size_t)(unsigned)(bj * 8 + w * 2 + ni) * 64) * 512 + (unsigned)lane * 8;

#define STAGE_A(BUF, IT)                                                     \
  do {                                                                       \
    _Pragma("unroll")                                                        \
    for (int q = 0; q < 2; ++q)                                              \
      gld_lds16(Xp + gA[q] + (unsigned)(IT) * 1024u, &As[BUF][loA[q]]);      \
  } while (0)

  short8 bc[2][2], bn[2][2];
  STAGE_A(0, 0);
#pragma unroll
  for (int ni = 0; ni < 2; ++ni)
#pragma unroll
    for (int kh = 0; kh < 2; ++kh)
      bc[ni][kh] = *(const short8*)(Bb[ni] + kh * 512);
  __syncthreads();                         // A(0) drained + sqi/sqj visible

  floatx4 acc[4][2] = {};

  for (int it = 0; it < NITER; ++it) {
    const int cur = it & 1;
    const bool has_next = (it + 1 < NITER);
    if (has_next) {
      STAGE_A(cur ^ 1, it + 1);            // async DMA into other buffer
#pragma unroll
      for (int ni = 0; ni < 2; ++ni)
#pragma unroll
        for (int kh = 0; kh < 2; ++kh)
          bn[ni][kh] = *(const short8*)(Bb[ni] + (unsigned)(it + 1) * 1024u + kh * 512);
    }

#pragma unroll
    for (int kh = 0; kh < 2; ++kh) {
      short8 af[4];
#pragma unroll
      for (int mi = 0; mi < 4; ++mi)
        af[mi] = *(const short8*)&As[cur][(mi * 2 + kh) * 512 + lane * 8];
#pragma unroll
      for (int mi = 0; mi < 4; ++mi)
#pragma unroll
        for (int ni = 0; ni < 2; ++ni)
          acc[mi][ni] = __builtin_amdgcn_mfma_f32_16x16x32_bf16(
              af[mi], bc[ni][kh], acc[mi][ni], 0, 0, 0);
    }

    // ONE barrier per iter: all waves' As[cur] reads done (safe to overwrite
    // next iter) AND the implicit vmcnt(0) drains the DMA into As[cur^1].
    __syncthreads();
    if (has_next) {
#pragma unroll
      for (int ni = 0; ni < 2; ++ni)
#pragma unroll
        for (int kh = 0; kh < 2; ++kh)
          bc[ni][kh] = bn[ni][kh];
    }
  }
#undef STAGE_A

  // Epilogue. C/D layout (m89): col = lane&15, row = (lane>>4)*4 + reg.
  const int cn = lane & 15, lg = lane >> 4;
  float sqc[2]; int labc[2];
#pragma unroll
  for (int ni = 0; ni < 2; ++ni) {
    int c = w * 32 + ni * 16 + cn;
    sqc[ni] = sqj[c]; labc[ni] = labj[c];
  }
  float cap[2] = {0.f, 0.f};
  float can[2] = {FLTMAX, FLTMAX};
#pragma unroll
  for (int mi = 0; mi < 4; ++mi) {
#pragma unroll
    for (int r = 0; r < 4; ++r) {
      const int rl = mi * 16 + lg * 4 + r;   // row within 64-tile
      const float si = sqi[rl];
      const int li = labi[rl];
      float apv = 0.0f;
      float anv = FLTMAX;
#pragma unroll
      for (int ni = 0; ni < 2; ++ni) {
        float g = acc[mi][ni][r];
        float d2 = fmaf(-2.0f, g, si + sqc[ni]);
        d2 = fmaxf(d2, 1e-12f);
        float d = __builtin_amdgcn_sqrtf(d2);
        const bool same = (li == labc[ni]);
        const float dp = same ? d : 0.0f;
        const float dn = same ? FLTMAX : d;
        apv = fmaxf(apv, dp);
        anv = fminf(anv, dn);
        cap[ni] = fmaxf(cap[ni], dp);   // col-side (symmetric) partials
        can[ni] = fminf(can[ni], dn);
      }
      // row side: reduce over the 16 cn-lanes (same lg = same row)
#pragma unroll
      for (int m = 8; m >= 1; m >>= 1) {
        apv = fmaxf(apv, __shfl_xor(apv, m, 64));
        anv = fminf(anv, __shfl_xor(anv, m, 64));
      }
      if (cn == 0) {
        int R = bi * 64 + rl;
        atomicMax(&ap[R], __float_as_uint(apv));
        atomicMin(&an[R], __float_as_uint(anv));
      }
    }
  }
  // col side: reduce over lg (xor 16,32) -> full 64 rows per column
#pragma unroll
  for (int ni = 0; ni < 2; ++ni) {
    float a = cap[ni], b = can[ni];
#pragma unroll
    for (int m = 16; m <= 32; m <<= 1) {
      a = fmaxf(a, __shfl_xor(a, m, 64));
      b = fminf(b, __shfl_xor(b, m, 64));
    }
    if (lg == 0) {
      int C = bj * 128 + w * 32 + ni * 16 + cn;
      atomicMax(&ap[C], __float_as_uint(a));
      atomicMin(&an[C], __float_as_uint(b));
    }
  }

  // ---- merged finalize: last block reduces loss ----
  __threadfence();                 // release: this block's atomics visible
  __syncthreads();                 // all waves' atomics issued+fenced
  __shared__ int lastflag;
  if (t == 0) {
    unsigned old = atomicAdd(counter, 1u);
    lastflag = (old == NBLOCKS - 1) ? 1 : 0;
  }
  __syncthreads();
  if (lastflag) {
    __threadfence();               // acquire: other blocks' atomics visible
    float s = 0.f;
#pragma unroll
    for (int q = 0; q < 16; ++q) {
      const int i = t + q * 256;
      // read via no-op atomic RMW: device-scope coherent across XCD L2s
      float a = __uint_as_float(atomicMax(&ap[i], 0u));
      float b = __uint_as_float(atomicMin(&an[i], 0x7f7fffffu));
      s += fmaxf(MARGIN + a - b, 0.0f);
    }
#pragma unroll
    for (int m = 32; m >= 1; m >>= 1) s += __shfl_down(s, m, 64);
    __shared__ float wsum[4];
    if (lane == 0) wsum[w] = s;
    __syncthreads();
    if (t == 0) out[0] = (wsum[0] + wsum[1] + wsum[2] + wsum[3]) * (1.0f / N_ROWS);
  }
}

extern "C" void kernel_launch(void* const* d_in, const int* in_sizes, int n_in,
                              void* d_out, int out_size, void* d_ws, size_t ws_size,
                              hipStream_t stream) {
  const float* X = (const float*)d_in[0];
  const int* lab = (const int*)d_in[1];
  float* out = (float*)d_out;

  char* ws = (char*)d_ws;
  unsigned short* Xp = (unsigned short*)ws;                            // 16 MB packed
  float* sq4 = (float*)(ws + (size_t)N_ROWS * N_DIM * 2);              // 64 KB (4 quarters)
  unsigned* ap = (unsigned*)((char*)sq4 + 4 * N_ROWS * sizeof(float)); // 16 KB
  unsigned* an = (unsigned*)((char*)ap + N_ROWS * sizeof(unsigned));   // 16 KB
  unsigned* counter = (unsigned*)((char*)an + N_ROWS * sizeof(unsigned)); // 4 B

  prep_kernel<<<N_ROWS / 16 * 4, 256, 0, stream>>>(X, Xp, sq4, ap, an, counter);
  dist_kernel<<<NBLOCKS, 256, 0, stream>>>(Xp, sq4, lab, ap, an, counter, out);
}

// Round 13
// 159.851 us; speedup vs baseline: 1.2751x; 1.2751x over previous
//
#include <hip/hip_runtime.h>
#include <stdint.h>

#define N_ROWS 4096
#define N_DIM  2048
#define MARGIN 0.3f
#define NITER  (N_DIM / 64)  // BK=64 -> 32 K-iterations
#define FLTMAX 3.402823466e+38f

// Tiling: 64 (A-rows) x 128 (B-cols) tiles. bi in [0,64), bj in [0,32),
// tiles with bi <= 2*bj+1 (covers all upper-triangle cells) -> 1056 blocks.
// XCD-paired decode (R9, measured: FETCH -18%): XCD x owns bj in
// {2x, 31-2x, 2x+1, 30-2x}.
#define NBI 64
#define NBJ 32
#define NBLOCKS 1056         // 132 x 8

typedef __attribute__((ext_vector_type(8))) short short8;
typedef __attribute__((ext_vector_type(4))) float floatx4;

// Packed layout ("fragment order"): for 16-row group g (256 total) and k-chunk
// c (32 k each, 64 total), a 1 KB block at shorts-offset (g*64+c)*512. Lane l's
// 16 B fragment at l*8 shorts = row g*16+(l&15), k c*32+(l>>4)*8..

__device__ inline unsigned short f2bf_rne(float f) {
  unsigned u = __float_as_uint(f);
  unsigned r = 0x7fffu + ((u >> 16) & 1u);
  return (unsigned short)((u + r) >> 16);
}
__device__ inline float bf2f(unsigned short h) {
  return __uint_as_float(((unsigned)h) << 16);
}

// Async global->LDS DMA, 16 B per lane. LDS dest = firstlane base + lane*16.
__device__ inline void gld_lds16(const void* g, void* l) {
  __builtin_amdgcn_global_load_lds(
      (const __attribute__((address_space(1))) void*)g,
      (__attribute__((address_space(3))) void*)l, 16, 0, 0);
}

// ---------------------------------------------------------------------------
// Kernel 1 (UNCHANGED from R12): TLP prep + absorbed init. 1024 blocks
// (4/CU); block (g = b>>2, cq = b&3) stages 32 KB fp32 via gld_lds, one
// barrier, convert+repack+store; sq quarter-partials NON-atomically to
// sq4[cq][row]; cq==0 blocks init ap/an; block 0 zeroes the counter.
// ---------------------------------------------------------------------------
__global__ __launch_bounds__(256) void prep_kernel(
    const float* __restrict__ X, unsigned short* __restrict__ Xp,
    float* __restrict__ sq4, unsigned* __restrict__ ap,
    unsigned* __restrict__ an, unsigned* __restrict__ counter)
{
  __shared__ __align__(16) float chunkf[8192];   // 32 KB: [row r][128 units]
  __shared__ float part[4][16];
  const int b = blockIdx.x;
  const int g = b >> 2, cq = b & 3;
  const int t = threadIdx.x;
  const int r = t & 15, j = (t >> 4) & 3, w = t >> 6;

  // Stage: rows [g*16,g*16+16) x bytes [cq*2048, cq*2048+2048) of each row.
  // LDS slot v (row rr=v>>7, unit m=v&127) holds global unit m^(rr&7) of the
  // row-quarter (source-side swizzle) -> b128 reads spread 8-way max.
  const char* Xb = (const char*)X + (size_t)g * 16 * 8192 + (size_t)cq * 2048;
#pragma unroll
  for (int q = 0; q < 8; ++q) {
    const unsigned v = q * 256 + t;
    const unsigned rr = v >> 7, m = v & 127;
    gld_lds16(Xb + (size_t)rr * 8192 + (size_t)(m ^ (rr & 7)) * 16,
              (char*)chunkf + (size_t)v * 16);
  }
  __syncthreads();   // full drain: all 16 rows staged; cross-wave reads safe

  unsigned short* Op = Xp + (size_t)g * 64 * 512 + (size_t)(j * 16 + r) * 8;
  float acc = 0.f;
#pragma unroll
  for (int sp = 0; sp < 4; ++sp) {
    const int cl = w + sp * 4;                   // local chunk in [0,16)
    const int c = cq * 16 + cl;                  // global chunk in [0,64)
    const unsigned m0 = (unsigned)cl * 8 + j * 2;  // 16B-unit within quarter-row
    const float4 v0 = *(const float4*)&chunkf[(r * 128 + (m0 ^ (r & 7))) * 4];
    const float4 v1 = *(const float4*)&chunkf[(r * 128 + ((m0 + 1) ^ (r & 7))) * 4];
    short8 o;
    o[0] = (short)f2bf_rne(v0.x); o[1] = (short)f2bf_rne(v0.y);
    o[2] = (short)f2bf_rne(v0.z); o[3] = (short)f2bf_rne(v0.w);
    o[4] = (short)f2bf_rne(v1.x); o[5] = (short)f2bf_rne(v1.y);
    o[6] = (short)f2bf_rne(v1.z); o[7] = (short)f2bf_rne(v1.w);
#pragma unroll
    for (int e = 0; e < 8; ++e) {
      float f = bf2f((unsigned short)o[e]);
      acc = fmaf(f, f, acc);
    }
    *(short8*)(Op + (size_t)c * 512) = o;
  }
  acc += __shfl_xor(acc, 16, 64);
  acc += __shfl_xor(acc, 32, 64);
  if ((t & 63) < 16) part[w][r] = acc;
  __syncthreads();
  if (t < 16) {
    float s4 = part[0][t] + part[1][t] + part[2][t] + part[3][t];
    sq4[cq * N_ROWS + g * 16 + t] = s4;          // non-atomic quarter partial
    if (cq == 0) {
      ap[g * 16 + t] = 0u;                       // max identity (dist >= 0)
      an[g * 16 + t] = 0x7f7fffffu;              // FLT_MAX bits
    }
  }
  if (b == 0 && t == 0) *counter = 0u;           // dist completion counter
}

// ---------------------------------------------------------------------------
// Kernel 2, R13 (= R12 dist, FENCE-FREE termination): R12's __threadfence
// emitted a per-block device-scope L2 writeback that serialized at each
// XCD's L2 (~132/XCD) and cost +80 us (measured: dist 57->138, utilizations
// halved, FETCH unchanged). Replacement ordering proof, no fence:
//   1. epilogue atomics are RETURNING (kept alive) -> their vmcnt retires
//      only when the RMW is performed at the device coherence point;
//   2. __syncthreads (implicit vmcnt(0)) -> ALL this block's RMWs performed;
//   3. t0 atomicAdd(counter): the block observing NBLOCKS-1 knows all
//      blocks' RMWs are complete; it reads ap/an via no-op atomic RMWs
//      (coherent-path reads, no stale XCD-L2 lines, G16) and reduces.
// ---------------------------------------------------------------------------
__global__ __launch_bounds__(256, 4) void dist_kernel(
    const unsigned short* __restrict__ Xp, const float* __restrict__ sq4,
    const int* __restrict__ lab, unsigned* __restrict__ ap,
    unsigned* __restrict__ an, unsigned* __restrict__ counter,
    float* __restrict__ out)
{
  __shared__ __align__(16) unsigned short As[2][4096];   // 2 x 8 KB (64 rows x 64 k)
  __shared__ float sqi[64], sqj[128];
  __shared__ int labi[64], labj[128];

  // R9 decode: x = target XCD (round-robin assumption), r = slot in [0,132).
  int bi, bj;
  {
    const int x = (int)(blockIdx.x & 7);
    int r = (int)(blockIdx.x >> 3);
    const int c0 = 4 * x + 2;            // bj = 2x      (bi <= 4x+1)
    const int c1 = 64 - 4 * x;           // bj = 31-2x   (bi <= 63-4x)
    const int c2 = 4 * x + 4;            // bj = 2x+1    (bi <= 4x+3)
    if (r < c0)                { bj = 2 * x;      bi = r; }
    else if (r < c0 + c1)      { bj = 31 - 2 * x; bi = r - c0; }
    else if (r < c0 + c1 + c2) { bj = 2 * x + 1;  bi = r - c0 - c1; }
    else                       { bj = 30 - 2 * x; bi = r - c0 - c1 - c2; }
  }

  const int t = threadIdx.x;
  const int lane = t & 63, w = t >> 6;     // 4 waves, 1x4 grid: wave w owns
                                           // cols [w*32, w*32+32), all 64 rows

  if (t < 64) {
    int rr = bi * 64 + t;
    sqi[t] = sq4[rr] + sq4[N_ROWS + rr] + sq4[2 * N_ROWS + rr] + sq4[3 * N_ROWS + rr];
    labi[t] = lab[rr];
  } else if (t < 192) {
    int cc = bj * 128 + (t - 64);
    sqj[t - 64] = sq4[cc] + sq4[N_ROWS + cc] + sq4[2 * N_ROWS + cc] + sq4[3 * N_ROWS + cc];
    labj[t - 64] = lab[cc];
  }

  // A staging: identity chunk map, 512 x 16B units (2/thread). unit u: group
  // gg = u>>7 (wave-uniform), off = u&127 (lane-contiguous) -> legal gld_lds.
  unsigned gA[2], loA[2];
#pragma unroll
  for (int q = 0; q < 2; ++q) {
    const unsigned u = q * 256 + t;
    gA[q] = ((unsigned)(bi * 4 + (u >> 7)) * 64) * 512 + (u & 127) * 8;
    loA[q] = u * 8;
  }
  // B direct: wave w's col 16-groups are (w*2) and (w*2+1). Fragment for
  // (ni, it, kh) at Bb[ni] + it*1024 + kh*512 (shorts), per-lane 16 B.
  const unsigned short* Bb[2];
#pragma unroll
  for (int ni = 0; ni < 2; ++ni)
    Bb[ni] = Xp + ((size_t)(unsigned)(bj * 8 + w * 2 + ni) * 64) * 512 + (unsigned)lane * 8;

#define STAGE_A(BUF, IT)                                                     \
  do {                                                                       \
    _Pragma("unroll")                                                        \
    for (int q = 0; q < 2; ++q)                                              \
      gld_lds16(Xp + gA[q] + (unsigned)(IT) * 1024u, &As[BUF][loA[q]]);      \
  } while (0)

  short8 bc[2][2], bn[2][2];
  STAGE_A(0, 0);
#pragma unroll
  for (int ni = 0; ni < 2; ++ni)
#pragma unroll
    for (int kh = 0; kh < 2; ++kh)
      bc[ni][kh] = *(const short8*)(Bb[ni] + kh * 512);
  __syncthreads();                         // A(0) drained + sqi/sqj visible

  floatx4 acc[4][2] = {};

  for (int it = 0; it < NITER; ++it) {
    const int cur = it & 1;
    const bool has_next = (it + 1 < NITER);
    if (has_next) {
      STAGE_A(cur ^ 1, it + 1);            // async DMA into other buffer
#pragma unroll
      for (int ni = 0; ni < 2; ++ni)
#pragma unroll
        for (int kh = 0; kh < 2; ++kh)
          bn[ni][kh] = *(const short8*)(Bb[ni] + (unsigned)(it + 1) * 1024u + kh * 512);
    }

#pragma unroll
    for (int kh = 0; kh < 2; ++kh) {
      short8 af[4];
#pragma unroll
      for (int mi = 0; mi < 4; ++mi)
        af[mi] = *(const short8*)&As[cur][(mi * 2 + kh) * 512 + lane * 8];
#pragma unroll
      for (int mi = 0; mi < 4; ++mi)
#pragma unroll
        for (int ni = 0; ni < 2; ++ni)
          acc[mi][ni] = __builtin_amdgcn_mfma_f32_16x16x32_bf16(
              af[mi], bc[ni][kh], acc[mi][ni], 0, 0, 0);
    }

    // ONE barrier per iter: all waves' As[cur] reads done (safe to overwrite
    // next iter) AND the implicit vmcnt(0) drains the DMA into As[cur^1].
    __syncthreads();
    if (has_next) {
#pragma unroll
      for (int ni = 0; ni < 2; ++ni)
#pragma unroll
        for (int kh = 0; kh < 2; ++kh)
          bc[ni][kh] = bn[ni][kh];
    }
  }
#undef STAGE_A

  // Epilogue. C/D layout (m89): col = lane&15, row = (lane>>4)*4 + reg.
  const int cn = lane & 15, lg = lane >> 4;
  float sqc[2]; int labc[2];
#pragma unroll
  for (int ni = 0; ni < 2; ++ni) {
    int c = w * 32 + ni * 16 + cn;
    sqc[ni] = sqj[c]; labc[ni] = labj[c];
  }
  float cap[2] = {0.f, 0.f};
  float can[2] = {FLTMAX, FLTMAX};
#pragma unroll
  for (int mi = 0; mi < 4; ++mi) {
#pragma unroll
    for (int r = 0; r < 4; ++r) {
      const int rl = mi * 16 + lg * 4 + r;   // row within 64-tile
      const float si = sqi[rl];
      const int li = labi[rl];
      float apv = 0.0f;
      float anv = FLTMAX;
#pragma unroll
      for (int ni = 0; ni < 2; ++ni) {
        float g = acc[mi][ni][r];
        float d2 = fmaf(-2.0f, g, si + sqc[ni]);
        d2 = fmaxf(d2, 1e-12f);
        float d = __builtin_amdgcn_sqrtf(d2);
        const bool same = (li == labc[ni]);
        const float dp = same ? d : 0.0f;
        const float dn = same ? FLTMAX : d;
        apv = fmaxf(apv, dp);
        anv = fminf(anv, dn);
        cap[ni] = fmaxf(cap[ni], dp);   // col-side (symmetric) partials
        can[ni] = fminf(can[ni], dn);
      }
      // row side: reduce over the 16 cn-lanes (same lg = same row)
#pragma unroll
      for (int m = 8; m >= 1; m >>= 1) {
        apv = fmaxf(apv, __shfl_xor(apv, m, 64));
        anv = fminf(anv, __shfl_xor(anv, m, 64));
      }
      if (cn == 0) {
        int R = bi * 64 + rl;
        unsigned o1 = atomicMax(&ap[R], __float_as_uint(apv));
        unsigned o2 = atomicMin(&an[R], __float_as_uint(anv));
        asm volatile("" :: "v"(o1), "v"(o2));   // returning form: vmcnt
                                                // retires on RMW completion
      }
    }
  }
  // col side: reduce over lg (xor 16,32) -> full 64 rows per column
#pragma unroll
  for (int ni = 0; ni < 2; ++ni) {
    float a = cap[ni], b = can[ni];
#pragma unroll
    for (int m = 16; m <= 32; m <<= 1) {
      a = fmaxf(a, __shfl_xor(a, m, 64));
      b = fminf(b, __shfl_xor(b, m, 64));
    }
    if (lg == 0) {
      int C = bj * 128 + w * 32 + ni * 16 + cn;
      unsigned o1 = atomicMax(&ap[C], __float_as_uint(a));
      unsigned o2 = atomicMin(&an[C], __float_as_uint(b));
      asm volatile("" :: "v"(o1), "v"(o2));
    }
  }

  // ---- merged finalize, fence-free: last block reduces loss ----
  __syncthreads();                 // vmcnt(0): this block's RMWs performed
  __shared__ int lastflag;
  if (t == 0) {
    unsigned old = atomicAdd(counter, 1u);
    lastflag = (old == NBLOCKS - 1) ? 1 : 0;
  }
  __syncthreads();
  if (lastflag) {
    float s = 0.f;
#pragma unroll
    for (int q = 0; q < 16; ++q) {
      const int i = t + q * 256;
      // read via no-op atomic RMW: coherent-path read across XCD L2s
      float a = __uint_as_float(atomicMax(&ap[i], 0u));
      float b = __uint_as_float(atomicMin(&an[i], 0x7f7fffffu));
      s += fmaxf(MARGIN + a - b, 0.0f);
    }
#pragma unroll
    for (int m = 32; m >= 1; m >>= 1) s += __shfl_down(s, m, 64);
    __shared__ float wsum[4];
    if (lane == 0) wsum[w] = s;
    __syncthreads();
    if (t == 0) out[0] = (wsum[0] + wsum[1] + wsum[2] + wsum[3]) * (1.0f / N_ROWS);
  }
}

extern "C" void kernel_launch(void* const* d_in, const int* in_sizes, int n_in,
                              void* d_out, int out_size, void* d_ws, size_t ws_size,
                              hipStream_t stream) {
  const float* X = (const float*)d_in[0];
  const int* lab = (const int*)d_in[1];
  float* out = (float*)d_out;

  char* ws = (char*)d_ws;
  unsigned short* Xp = (unsigned short*)ws;                            // 16 MB packed
  float* sq4 = (float*)(ws + (size_t)N_ROWS * N_DIM * 2);              // 64 KB (4 quarters)
  unsigned* ap = (unsigned*)((char*)sq4 + 4 * N_ROWS * sizeof(float)); // 16 KB
  unsigned* an = (unsigned*)((char*)ap + N_ROWS * sizeof(unsigned));   // 16 KB
  unsigned* counter = (unsigned*)((char*)an + N_ROWS * sizeof(unsigned)); // 4 B

  prep_kernel<<<N_ROWS / 16 * 4, 256, 0, stream>>>(X, Xp, sq4, ap, an, counter);
  dist_kernel<<<NBLOCKS, 256, 0, stream>>>(Xp, sq4, lab, ap, an, counter, out);
}

// Round 14
// 129.417 us; speedup vs baseline: 1.5749x; 1.2352x over previous
//
#include <hip/hip_runtime.h>
#include <stdint.h>

#define N_ROWS 4096
#define N_DIM  2048
#define MARGIN 0.3f
#define NITER  (N_DIM / 64)  // BK=64 -> 32 K-iterations
#define FLTMAX 3.402823466e+38f

// Tiling: 64 (A-rows) x 128 (B-cols) tiles. bi in [0,64), bj in [0,32),
// tiles with bi <= 2*bj+1 (covers all upper-triangle cells) -> 1056 blocks.
// XCD-paired decode (R9, measured: FETCH -18%): XCD x owns bj in
// {2x, 31-2x, 2x+1, 30-2x}.
#define NBI 64
#define NBJ 32
#define NBLOCKS 1056         // 132 x 8

typedef __attribute__((ext_vector_type(8))) short short8;
typedef __attribute__((ext_vector_type(4))) float floatx4;

// Packed layout ("fragment order"): for 16-row group g (256 total) and k-chunk
// c (32 k each, 64 total), a 1 KB block at shorts-offset (g*64+c)*512. Lane l's
// 16 B fragment at l*8 shorts = row g*16+(l&15), k c*32+(l>>4)*8..

__device__ inline unsigned short f2bf_rne(float f) {
  unsigned u = __float_as_uint(f);
  unsigned r = 0x7fffu + ((u >> 16) & 1u);
  return (unsigned short)((u + r) >> 16);
}
__device__ inline float bf2f(unsigned short h) {
  return __uint_as_float(((unsigned)h) << 16);
}

// Async global->LDS DMA, 16 B per lane. LDS dest = firstlane base + lane*16.
__device__ inline void gld_lds16(const void* g, void* l) {
  __builtin_amdgcn_global_load_lds(
      (const __attribute__((address_space(1))) void*)g,
      (__attribute__((address_space(3))) void*)l, 16, 0, 0);
}

// ---------------------------------------------------------------------------
// Kernel 1 (R12 prep, counter removed): TLP prep + absorbed init. 1024
// blocks (4/CU); block (g = b>>2, cq = b&3) stages 32 KB fp32 via gld_lds,
// one barrier, convert+repack+store; sq quarter-partials NON-atomically to
// sq4[cq][row]; cq==0 blocks init ap/an. Same-stream ordering makes the
// init race-free. (R12/R13 showed this prep is harmless; the regression
// lived entirely in dist's merged finalize.)
// ---------------------------------------------------------------------------
__global__ __launch_bounds__(256) void prep_kernel(
    const float* __restrict__ X, unsigned short* __restrict__ Xp,
    float* __restrict__ sq4, unsigned* __restrict__ ap,
    unsigned* __restrict__ an)
{
  __shared__ __align__(16) float chunkf[8192];   // 32 KB: [row r][128 units]
  __shared__ float part[4][16];
  const int b = blockIdx.x;
  const int g = b >> 2, cq = b & 3;
  const int t = threadIdx.x;
  const int r = t & 15, j = (t >> 4) & 3, w = t >> 6;

  // Stage: rows [g*16,g*16+16) x bytes [cq*2048, cq*2048+2048) of each row.
  // LDS slot v (row rr=v>>7, unit m=v&127) holds global unit m^(rr&7) of the
  // row-quarter (source-side swizzle) -> b128 reads spread 8-way max.
  const char* Xb = (const char*)X + (size_t)g * 16 * 8192 + (size_t)cq * 2048;
#pragma unroll
  for (int q = 0; q < 8; ++q) {
    const unsigned v = q * 256 + t;
    const unsigned rr = v >> 7, m = v & 127;
    gld_lds16(Xb + (size_t)rr * 8192 + (size_t)(m ^ (rr & 7)) * 16,
              (char*)chunkf + (size_t)v * 16);
  }
  __syncthreads();   // full drain: all 16 rows staged; cross-wave reads safe

  unsigned short* Op = Xp + (size_t)g * 64 * 512 + (size_t)(j * 16 + r) * 8;
  float acc = 0.f;
#pragma unroll
  for (int sp = 0; sp < 4; ++sp) {
    const int cl = w + sp * 4;                   // local chunk in [0,16)
    const int c = cq * 16 + cl;                  // global chunk in [0,64)
    const unsigned m0 = (unsigned)cl * 8 + j * 2;  // 16B-unit within quarter-row
    const float4 v0 = *(const float4*)&chunkf[(r * 128 + (m0 ^ (r & 7))) * 4];
    const float4 v1 = *(const float4*)&chunkf[(r * 128 + ((m0 + 1) ^ (r & 7))) * 4];
    short8 o;
    o[0] = (short)f2bf_rne(v0.x); o[1] = (short)f2bf_rne(v0.y);
    o[2] = (short)f2bf_rne(v0.z); o[3] = (short)f2bf_rne(v0.w);
    o[4] = (short)f2bf_rne(v1.x); o[5] = (short)f2bf_rne(v1.y);
    o[6] = (short)f2bf_rne(v1.z); o[7] = (short)f2bf_rne(v1.w);
#pragma unroll
    for (int e = 0; e < 8; ++e) {
      float f = bf2f((unsigned short)o[e]);
      acc = fmaf(f, f, acc);
    }
    *(short8*)(Op + (size_t)c * 512) = o;
  }
  acc += __shfl_xor(acc, 16, 64);
  acc += __shfl_xor(acc, 32, 64);
  if ((t & 63) < 16) part[w][r] = acc;
  __syncthreads();
  if (t < 16) {
    float s4 = part[0][t] + part[1][t] + part[2][t] + part[3][t];
    sq4[cq * N_ROWS + g * 16 + t] = s4;          // non-atomic quarter partial
    if (cq == 0) {
      ap[g * 16 + t] = 0u;                       // max identity (dist >= 0)
      an[g * 16 + t] = 0x7f7fffffu;              // FLT_MAX bits
    }
  }
}

// ---------------------------------------------------------------------------
// Kernel 2 (EXACT R11 dist — best measured: 57.1 us): 64x128 tile, 1x4 wave
// grid, acc[4][2], A in LDS dbuf via gld_lds (one __syncthreads/iter), B
// direct global->register prefetch, XCD-paired decode. sqi/sqj sum the 4
// sq4 quarters at load (benign; ran in R12/R13 main loop at no cost).
// Epilogue atomics are fire-and-forget (NON-returning — R13's returning
// form + counter protocol cost +31 us). No termination protocol; finalize
// is a separate dispatch again.
// ---------------------------------------------------------------------------
__global__ __launch_bounds__(256, 4) void dist_kernel(
    const unsigned short* __restrict__ Xp, const float* __restrict__ sq4,
    const int* __restrict__ lab, unsigned* __restrict__ ap,
    unsigned* __restrict__ an)
{
  __shared__ __align__(16) unsigned short As[2][4096];   // 2 x 8 KB (64 rows x 64 k)
  __shared__ float sqi[64], sqj[128];
  __shared__ int labi[64], labj[128];

  // R9 decode: x = target XCD (round-robin assumption), r = slot in [0,132).
  int bi, bj;
  {
    const int x = (int)(blockIdx.x & 7);
    int r = (int)(blockIdx.x >> 3);
    const int c0 = 4 * x + 2;            // bj = 2x      (bi <= 4x+1)
    const int c1 = 64 - 4 * x;           // bj = 31-2x   (bi <= 63-4x)
    const int c2 = 4 * x + 4;            // bj = 2x+1    (bi <= 4x+3)
    if (r < c0)                { bj = 2 * x;      bi = r; }
    else if (r < c0 + c1)      { bj = 31 - 2 * x; bi = r - c0; }
    else if (r < c0 + c1 + c2) { bj = 2 * x + 1;  bi = r - c0 - c1; }
    else                       { bj = 30 - 2 * x; bi = r - c0 - c1 - c2; }
  }

  const int t = threadIdx.x;
  const int lane = t & 63, w = t >> 6;     // 4 waves, 1x4 grid: wave w owns
                                           // cols [w*32, w*32+32), all 64 rows

  if (t < 64) {
    int rr = bi * 64 + t;
    sqi[t] = sq4[rr] + sq4[N_ROWS + rr] + sq4[2 * N_ROWS + rr] + sq4[3 * N_ROWS + rr];
    labi[t] = lab[rr];
  } else if (t < 192) {
    int cc = bj * 128 + (t - 64);
    sqj[t - 64] = sq4[cc] + sq4[N_ROWS + cc] + sq4[2 * N_ROWS + cc] + sq4[3 * N_ROWS + cc];
    labj[t - 64] = lab[cc];
  }

  // A staging: identity chunk map, 512 x 16B units (2/thread). unit u: group
  // gg = u>>7 (wave-uniform), off = u&127 (lane-contiguous) -> legal gld_lds.
  unsigned gA[2], loA[2];
#pragma unroll
  for (int q = 0; q < 2; ++q) {
    const unsigned u = q * 256 + t;
    gA[q] = ((unsigned)(bi * 4 + (u >> 7)) * 64) * 512 + (u & 127) * 8;
    loA[q] = u * 8;
  }
  // B direct: wave w's col 16-groups are (w*2) and (w*2+1). Fragment for
  // (ni, it, kh) at Bb[ni] + it*1024 + kh*512 (shorts), per-lane 16 B.
  const unsigned short* Bb[2];
#pragma unroll
  for (int ni = 0; ni < 2; ++ni)
    Bb[ni] = Xp + ((size_t)(unsigned)(bj * 8 + w * 2 + ni) * 64) * 512 + (unsigned)lane * 8;

#define STAGE_A(BUF, IT)                                                     \
  do {                                                                       \
    _Pragma("unroll")                                                        \
    for (int q = 0; q < 2; ++q)                                              \
      gld_lds16(Xp + gA[q] + (unsigned)(IT) * 1024u, &As[BUF][loA[q]]);      \
  } while (0)

  short8 bc[2][2], bn[2][2];
  STAGE_A(0, 0);
#pragma unroll
  for (int ni = 0; ni < 2; ++ni)
#pragma unroll
    for (int kh = 0; kh < 2; ++kh)
      bc[ni][kh] = *(const short8*)(Bb[ni] + kh * 512);
  __syncthreads();                         // A(0) drained + sqi/sqj visible

  floatx4 acc[4][2] = {};

  for (int it = 0; it < NITER; ++it) {
    const int cur = it & 1;
    const bool has_next = (it + 1 < NITER);
    if (has_next) {
      STAGE_A(cur ^ 1, it + 1);            // async DMA into other buffer
#pragma unroll
      for (int ni = 0; ni < 2; ++ni)
#pragma unroll
        for (int kh = 0; kh < 2; ++kh)
          bn[ni][kh] = *(const short8*)(Bb[ni] + (unsigned)(it + 1) * 1024u + kh * 512);
    }

#pragma unroll
    for (int kh = 0; kh < 2; ++kh) {
      short8 af[4];
#pragma unroll
      for (int mi = 0; mi < 4; ++mi)
        af[mi] = *(const short8*)&As[cur][(mi * 2 + kh) * 512 + lane * 8];
#pragma unroll
      for (int mi = 0; mi < 4; ++mi)
#pragma unroll
        for (int ni = 0; ni < 2; ++ni)
          acc[mi][ni] = __builtin_amdgcn_mfma_f32_16x16x32_bf16(
              af[mi], bc[ni][kh], acc[mi][ni], 0, 0, 0);
    }

    // ONE barrier per iter: all waves' As[cur] reads done (safe to overwrite
    // next iter) AND the implicit vmcnt(0) drains the DMA into As[cur^1].
    __syncthreads();
    if (has_next) {
#pragma unroll
      for (int ni = 0; ni < 2; ++ni)
#pragma unroll
        for (int kh = 0; kh < 2; ++kh)
          bc[ni][kh] = bn[ni][kh];
    }
  }
#undef STAGE_A

  // Epilogue. C/D layout (m89): col = lane&15, row = (lane>>4)*4 + reg.
  const int cn = lane & 15, lg = lane >> 4;
  float sqc[2]; int labc[2];
#pragma unroll
  for (int ni = 0; ni < 2; ++ni) {
    int c = w * 32 + ni * 16 + cn;
    sqc[ni] = sqj[c]; labc[ni] = labj[c];
  }
  float cap[2] = {0.f, 0.f};
  float can[2] = {FLTMAX, FLTMAX};
#pragma unroll
  for (int mi = 0; mi < 4; ++mi) {
#pragma unroll
    for (int r = 0; r < 4; ++r) {
      const int rl = mi * 16 + lg * 4 + r;   // row within 64-tile
      const float si = sqi[rl];
      const int li = labi[rl];
      float apv = 0.0f;
      float anv = FLTMAX;
#pragma unroll
      for (int ni = 0; ni < 2; ++ni) {
        float g = acc[mi][ni][r];
        float d2 = fmaf(-2.0f, g, si + sqc[ni]);
        d2 = fmaxf(d2, 1e-12f);
        float d = __builtin_amdgcn_sqrtf(d2);
        const bool same = (li == labc[ni]);
        const float dp = same ? d : 0.0f;
        const float dn = same ? FLTMAX : d;
        apv = fmaxf(apv, dp);
        anv = fminf(anv, dn);
        cap[ni] = fmaxf(cap[ni], dp);   // col-side (symmetric) partials
        can[ni] = fminf(can[ni], dn);
      }
      // row side: reduce over the 16 cn-lanes (same lg = same row)
#pragma unroll
      for (int m = 8; m >= 1; m >>= 1) {
        apv = fmaxf(apv, __shfl_xor(apv, m, 64));
        anv = fminf(anv, __shfl_xor(anv, m, 64));
      }
      if (cn == 0) {
        int R = bi * 64 + rl;
        atomicMax(&ap[R], __float_as_uint(apv));
        atomicMin(&an[R], __float_as_uint(anv));
      }
    }
  }
  // col side: reduce over lg (xor 16,32) -> full 64 rows per column
#pragma unroll
  for (int ni = 0; ni < 2; ++ni) {
    float a = cap[ni], b = can[ni];
#pragma unroll
    for (int m = 16; m <= 32; m <<= 1) {
      a = fmaxf(a, __shfl_xor(a, m, 64));
      b = fminf(b, __shfl_xor(b, m, 64));
    }
    if (lg == 0) {
      int C = bj * 128 + w * 32 + ni * 16 + cn;
      atomicMax(&ap[C], __float_as_uint(a));
      atomicMin(&an[C], __float_as_uint(b));
    }
  }
}

// ---------------------------------------------------------------------------
// Kernel 3 (R4 finalize): loss = mean(relu(margin + dist_ap - dist_an))
// ---------------------------------------------------------------------------
__global__ __launch_bounds__(256) void finalize_kernel(
    const unsigned* __restrict__ ap, const unsigned* __restrict__ an,
    float* __restrict__ out)
{
  const int t = threadIdx.x;
  float av[16], bv[16];
#pragma unroll
  for (int q = 0; q < 16; ++q) {
    av[q] = __uint_as_float(ap[t + q * 256]);
    bv[q] = __uint_as_float(an[t + q * 256]);
  }
  float s = 0.f;
#pragma unroll
  for (int q = 0; q < 16; ++q) s += fmaxf(MARGIN + av[q] - bv[q], 0.0f);
#pragma unroll
  for (int m = 32; m >= 1; m >>= 1) s += __shfl_down(s, m, 64);
  __shared__ float wsum[4];
  const int lane = t & 63, w = t >> 6;
  if (lane == 0) wsum[w] = s;
  __syncthreads();
  if (t == 0) out[0] = (wsum[0] + wsum[1] + wsum[2] + wsum[3]) * (1.0f / N_ROWS);
}

extern "C" void kernel_launch(void* const* d_in, const int* in_sizes, int n_in,
                              void* d_out, int out_size, void* d_ws, size_t ws_size,
                              hipStream_t stream) {
  const float* X = (const float*)d_in[0];
  const int* lab = (const int*)d_in[1];
  float* out = (float*)d_out;

  char* ws = (char*)d_ws;
  unsigned short* Xp = (unsigned short*)ws;                            // 16 MB packed
  float* sq4 = (float*)(ws + (size_t)N_ROWS * N_DIM * 2);              // 64 KB (4 quarters)
  unsigned* ap = (unsigned*)((char*)sq4 + 4 * N_ROWS * sizeof(float)); // 16 KB
  unsigned* an = (unsigned*)((char*)ap + N_ROWS * sizeof(unsigned));   // 16 KB

  prep_kernel<<<N_ROWS / 16 * 4, 256, 0, stream>>>(X, Xp, sq4, ap, an);
  dist_kernel<<<NBLOCKS, 256, 0, stream>>>(Xp, sq4, lab, ap, an);
  finalize_kernel<<<1, 256, 0, stream>>>(ap, an, out);
}